// Round 8
// baseline (96.487 us; speedup 1.0000x reference)
//
#include <hip/hip_runtime.h>
#include <hip/hip_cooperative_groups.h>
#include <math.h>

namespace cg = cooperative_groups;

// Realspace Ewald: pot = 2 * sum_{i<j} q_i q_j erf(d_ij/sqrt(2))/d_ij * NORM/(4pi)
// N=6144. VALU-bound. erf via A&S rational form (no exp2; absmax 0.0 since R6).
// One 64x64 triangle tile per wave (R7). SINGLE cooperative kernel: partials ->
// grid.sync() -> block 0 reduces (deterministic fixed order). Kills the 2nd
// dispatch + inter-kernel gap (~5us structural tail).

#if __has_builtin(__builtin_amdgcn_rsqf)
#define FRSQ(x) __builtin_amdgcn_rsqf(x)
#else
#define FRSQ(x) rsqrtf(x)
#endif
#if __has_builtin(__builtin_amdgcn_rcpf)
#define FRCP(x) __builtin_amdgcn_rcpf(x)
#else
#define FRCP(x) (1.0f / (x))
#endif

// A&S 7.1.23 coefficients pre-multiplied by (1/sqrt(2))^k so poly is in d:
#define B1 0.19685360f
#define B2 0.11519450f
#define B3 0.00034366f
#define B4 0.01952700f

template <bool CHECK>
__device__ __forceinline__ void pair_body(const float4 v, int k, int lane,
                                          float xi, float yi, float zi,
                                          float& acc) {
  float dx = xi - v.x;
  float dy = yi - v.y;
  float dz = zi - v.z;
  float d2 = fmaf(dx, dx, fmaf(dy, dy, dz * dz));
  float qk = v.w;
  if (CHECK) {
    bool take = (k > lane);  // diagonal tile: j>i <=> k>lane
    d2 = take ? d2 : 1.0f;
    qk = take ? qk : 0.0f;
  }
  float rinv = FRSQ(d2);
  float d = d2 * rinv;
  // erf(d/sqrt2) = 1 - 1/(1 + b1 d + b2 d^2 + b3 d^3 + b4 d^4)^4
  float poly = fmaf(fmaf(fmaf(B4, d, B3), d, B2), d, B1);
  poly = fmaf(poly, d, 1.0f);
  float y = FRCP(poly);
  float y2 = y * y;
  float y4 = y2 * y2;
  float w = fmaf(-y4, rinv, rinv);  // erf(d/sqrt2)/d
  acc = fmaf(qk, w, acc);
}

template <bool CHECK>
__device__ __forceinline__ float tile_sum(const float4* __restrict__ tile,
                                          int lane, float xi, float yi,
                                          float zi) {
  float acc0 = 0.f, acc1 = 0.f;
#pragma unroll 8
  for (int k = 0; k < 64; k += 2) {
    pair_body<CHECK>(tile[k], k, lane, xi, yi, zi, acc0);
    pair_body<CHECK>(tile[k + 1], k + 1, lane, xi, yi, zi, acc1);
  }
  return acc0 + acc1;
}

__global__ __launch_bounds__(256) void ewald_fused(
    const float* __restrict__ q, const float* __restrict__ r,
    float* __restrict__ partial, float* __restrict__ out, int n, int nt,
    int ntiles, float scale) {
  const int tid = threadIdx.x;
  const int lane = tid & 63;
  const int wid = tid >> 6;
  const int g = blockIdx.x * 4 + wid;  // global tile id (wave-uniform)

  __shared__ float4 tile[4][64];

  if (g < ntiles) {
    // invert g -> (ti, tj), upper triangle incl. diagonal, row-major
    const float a = (float)nt + 0.5f;
    int ti = (int)(a - sqrtf(fmaf(a, a, -2.0f * (float)g)));
    if (ti < 0) ti = 0;
    if (ti >= nt) ti = nt - 1;
#define CUM(t) ((t) * nt - ((t) * ((t)-1)) / 2)
    while (CUM(ti + 1) <= g) ++ti;
    while (CUM(ti) > g) --ti;
    const int tj = ti + (g - CUM(ti));
#undef CUM

    const int ibeg = ti << 6;
    const int jbeg = tj << 6;

    // stage this wave's j-tile into its private LDS quadrant (no barriers:
    // same-wave ds ordering via lgkmcnt)
    {
      int j = jbeg + lane;
      float4 v = make_float4(1e10f, 1e10f, 1e10f, 0.f);
      if (j < n) v = make_float4(r[3 * j], r[3 * j + 1], r[3 * j + 2], q[j]);
      tile[wid][lane] = v;
    }

    const int i = ibeg + lane;
    float qi = 0.f, xi = 1e10f, yi = 1e10f, zi = 1e10f;
    if (i < n) {
      qi = q[i];
      xi = r[3 * i];
      yi = r[3 * i + 1];
      zi = r[3 * i + 2];
    }

    float acc;
    if (ti == tj)
      acc = tile_sum<true>(tile[wid], lane, xi, yi, zi);
    else
      acc = tile_sum<false>(tile[wid], lane, xi, yi, zi);
    acc *= qi;

    // in-wave shfl reduce; lane 0 stores this tile's partial
    for (int m = 32; m > 0; m >>= 1) acc += __shfl_xor(acc, m, 64);
    if (lane == 0) partial[g] = acc;
  }

  // grid-wide barrier (all threads participate)
  cg::this_grid().sync();

  // block 0 reduces all partials (deterministic fixed order)
  if (blockIdx.x == 0) {
    float a2 = 0.f;
    for (int idx = tid; idx < ntiles; idx += 256) a2 += partial[idx];
    for (int m = 32; m > 0; m >>= 1) a2 += __shfl_xor(a2, m, 64);
    __shared__ float wsum2[4];
    if (lane == 0) wsum2[wid] = a2;
    __syncthreads();
    if (tid == 0)
      out[0] = ((wsum2[0] + wsum2[1]) + (wsum2[2] + wsum2[3])) * scale;
  }
}

extern "C" void kernel_launch(void* const* d_in, const int* in_sizes, int n_in,
                              void* d_out, int out_size, void* d_ws,
                              size_t ws_size, hipStream_t stream) {
  const float* q = (const float*)d_in[0];  // [N,1] fp32
  const float* r = (const float*)d_in[1];  // [N,3] fp32
  int n = in_sizes[0];
  float* out = (float*)d_out;
  float* partial = (float*)d_ws;

  int nt = (n + 63) / 64;              // 96 tiles per axis
  int ntiles = nt * (nt + 1) / 2;      // 4656 triangle tiles
  const int nblocks = (ntiles + 3) / 4;

  // 2 (triangle symmetry) * NORM/(2pi)/2 = NORM/(2pi)
  float scale = (float)(90.0474 / (2.0 * M_PI));

  void* args[] = {(void*)&q, (void*)&r, (void*)&partial, (void*)&out,
                  (void*)&n, (void*)&nt, (void*)&ntiles, (void*)&scale};
  hipLaunchCooperativeKernel((const void*)ewald_fused, dim3(nblocks), dim3(256),
                             args, 0, stream);
}

// Round 9
// 21.090 us; speedup vs baseline: 4.5750x; 4.5750x over previous
//
#include <hip/hip_runtime.h>
#include <math.h>

// Realspace Ewald: pot = 2 * sum_{i<j} q_i q_j erf(d_ij/sqrt(2))/d_ij * NORM/(4pi)
// N=6144. erf via A&S 7.1.23 rational form (no exp2; absmax 0.0 since R6).
// R9: j-tile lives in 4 VGPRs per wave (lane l = particle jbeg+l); inner loop
// fully unrolled, particle k broadcast via v_readlane with CONSTANT lane index
// -- zero LDS traffic in the inner loop (R6 was LDS-pipe-co-bound: one
// ds_read_b128 (~12cyc) per wave-iter x 4 SIMDs sharing one LDS pipe).
// 4 accumulators for ILP. 1D grid over 1200 active triangle tiles; 2 kernels
// (coop grid.sync cost 60us: R8; memset-in-graph cost 39us: R4).

#if __has_builtin(__builtin_amdgcn_rsqf)
#define FRSQ(x) __builtin_amdgcn_rsqf(x)
#else
#define FRSQ(x) rsqrtf(x)
#endif
#if __has_builtin(__builtin_amdgcn_rcpf)
#define FRCP(x) __builtin_amdgcn_rcpf(x)
#else
#define FRCP(x) (1.0f / (x))
#endif

#define RDLANE(v, k) __int_as_float(__builtin_amdgcn_readlane(__float_as_int(v), (k)))

// A&S 7.1.23 coefficients pre-multiplied by (1/sqrt(2))^k so poly is in d:
#define B1 0.19685360f
#define B2 0.11519450f
#define B3 0.00034366f
#define B4 0.01952700f

template <bool CHECK>
__device__ __forceinline__ void pair_body(float sx, float sy, float sz,
                                          float sq, int jj, int i, float xi,
                                          float yi, float zi, float& acc) {
  float dx = xi - sx;
  float dy = yi - sy;
  float dz = zi - sz;
  float d2 = fmaf(dx, dx, fmaf(dy, dy, dz * dz));
  float qk = sq;
  if (CHECK) {
    bool take = (jj > i);    // triangle + diagonal guard
    d2 = take ? d2 : 1.0f;   // keep rsq well-defined
    qk = take ? qk : 0.0f;
  }
  float rinv = FRSQ(d2);
  float d = d2 * rinv;
  // erf(d/sqrt2) = 1 - 1/(1 + b1 d + b2 d^2 + b3 d^3 + b4 d^4)^4
  float poly = fmaf(fmaf(fmaf(B4, d, B3), d, B2), d, B1);
  poly = fmaf(poly, d, 1.0f);
  float y = FRCP(poly);
  float y2 = y * y;
  float y4 = y2 * y2;
  float w = fmaf(-y4, rinv, rinv);  // erf(d/sqrt2)/d
  acc = fmaf(qk, w, acc);
}

template <bool CHECK>
__device__ __forceinline__ float tile_sum(float jx, float jy, float jz,
                                          float jq, int jbeg, int i, float xi,
                                          float yi, float zi) {
  float acc0 = 0.f, acc1 = 0.f, acc2 = 0.f, acc3 = 0.f;
#pragma unroll
  for (int k = 0; k < 64; ++k) {
    // k is compile-time constant after full unroll -> v_readlane with
    // constant lane index; no LDS, exec-independent.
    float sx = RDLANE(jx, k);
    float sy = RDLANE(jy, k);
    float sz = RDLANE(jz, k);
    float sq = RDLANE(jq, k);
    float& a = (k & 1) ? ((k & 2) ? acc3 : acc1) : ((k & 2) ? acc2 : acc0);
    pair_body<CHECK>(sx, sy, sz, sq, jbeg + k, i, xi, yi, zi, a);
  }
  return (acc0 + acc1) + (acc2 + acc3);
}

__global__ __launch_bounds__(256) void ewald_tri(
    const float* __restrict__ q, const float* __restrict__ r,
    float* __restrict__ partial, int n) {
  const int tid = threadIdx.x;
  const int bid = blockIdx.x;
  const int lane = tid & 63;
  const int wid = tid >> 6;
  const int jslices = (n + 63) >> 6;

  // invert bid -> (ib, js): active js for i-block ib are [4*ib, jslices)
  int ib = 0, cum = 0;
  while (true) {
    int c = jslices - 4 * ib;
    if (c <= 0 || cum + c > bid) break;
    cum += c;
    ++ib;
  }
  const int js = 4 * ib + (bid - cum);

  const int ibeg = ib << 8;
  const int jbeg = js << 6;
  const bool pure_above = (jbeg >= ibeg + 256);

  // this wave's copy of the j-tile, in registers: lane l holds particle jbeg+l
  float jx = 1e10f, jy = 1e10f, jz = 1e10f, jq = 0.f;
  {
    int j = jbeg + lane;
    if (j < n) {
      jx = r[3 * j];
      jy = r[3 * j + 1];
      jz = r[3 * j + 2];
      jq = q[j];
    }
  }

  const int i = ibeg + tid;
  float qi = 0.f, xi = 1e10f, yi = 1e10f, zi = 1e10f;
  if (i < n) {
    qi = q[i];
    xi = r[3 * i];
    yi = r[3 * i + 1];
    zi = r[3 * i + 2];
  }

  float acc;
  if (pure_above)
    acc = tile_sum<false>(jx, jy, jz, jq, jbeg, i, xi, yi, zi);
  else
    acc = tile_sum<true>(jx, jy, jz, jq, jbeg, i, xi, yi, zi);
  acc *= qi;

  // deterministic block reduce: wave shfl, then cross-wave via LDS
  for (int m = 32; m > 0; m >>= 1) acc += __shfl_xor(acc, m, 64);
  __shared__ float wsum[4];
  if (lane == 0) wsum[wid] = acc;
  __syncthreads();
  if (tid == 0)
    partial[bid] = (wsum[0] + wsum[1]) + (wsum[2] + wsum[3]);
}

__global__ __launch_bounds__(1024) void reduce_partials(
    const float* __restrict__ partial, float* __restrict__ out, int np,
    float scale) {
  const int tid = threadIdx.x;
  float acc = 0.f;
  for (int idx = tid; idx < np; idx += 1024) acc += partial[idx];
  for (int m = 32; m > 0; m >>= 1) acc += __shfl_xor(acc, m, 64);
  __shared__ float wsum[16];
  const int lane = tid & 63;
  const int wid = tid >> 6;
  if (lane == 0) wsum[wid] = acc;
  __syncthreads();
  if (tid == 0) {
    float s = 0.f;
    for (int w = 0; w < 16; ++w) s += wsum[w];
    out[0] = s * scale;
  }
}

extern "C" void kernel_launch(void* const* d_in, const int* in_sizes, int n_in,
                              void* d_out, int out_size, void* d_ws,
                              size_t ws_size, hipStream_t stream) {
  const float* q = (const float*)d_in[0];  // [N,1] fp32
  const float* r = (const float*)d_in[1];  // [N,3] fp32
  const int n = in_sizes[0];
  float* out = (float*)d_out;
  float* partial = (float*)d_ws;

  const int iblocks = (n + 255) / 256;
  const int jslices = (n + 63) / 64;
  int nblocks = 0;
  for (int ib = 0; ib < iblocks; ++ib) {
    int c = jslices - 4 * ib;
    if (c > 0) nblocks += c;
  }

  ewald_tri<<<nblocks, 256, 0, stream>>>(q, r, partial, n);

  // 2 (triangle symmetry) * NORM/(2pi)/2 = NORM/(2pi)
  const float scale = (float)(90.0474 / (2.0 * M_PI));
  reduce_partials<<<1, 1024, 0, stream>>>(partial, out, nblocks, scale);
}

// Round 10
// 17.662 us; speedup vs baseline: 5.4631x; 1.1941x over previous
//
#include <hip/hip_runtime.h>
#include <math.h>

// Realspace Ewald: pot = 2 * sum_{i<j} q_i q_j erf(d_ij/sqrt(2))/d_ij * NORM/(4pi)
// N=6144. erf via A&S 7.1.23 rational form (no exp2; absmax 0.0 since R6).
// R10: latency-hiding round. Evidence: R7 (block overhead) neutral, R9 (LDS
// removal) regressed, VGPR=16 in all profiles -> inner loop is dependency-
// chain-latency bound (d2->rsq->poly->rcp chain ~55cyc, only 2 chains live).
// Fix: 4 accumulator chains (stride-4) + 32-wide j-tiles (2400 blocks,
// 9.4 waves/SIMD vs 4.7) for 2x TLP. LDS j-tile staged once (R6-proven).

#if __has_builtin(__builtin_amdgcn_rsqf)
#define FRSQ(x) __builtin_amdgcn_rsqf(x)
#else
#define FRSQ(x) rsqrtf(x)
#endif
#if __has_builtin(__builtin_amdgcn_rcpf)
#define FRCP(x) __builtin_amdgcn_rcpf(x)
#else
#define FRCP(x) (1.0f / (x))
#endif

// A&S 7.1.23 coefficients pre-multiplied by (1/sqrt(2))^k so poly is in d:
#define B1 0.19685360f
#define B2 0.11519450f
#define B3 0.00034366f
#define B4 0.01952700f

template <bool CHECK>
__device__ __forceinline__ void pair_body(const float4 v, int jj, int i,
                                          float xi, float yi, float zi,
                                          float& acc) {
  float dx = xi - v.x;
  float dy = yi - v.y;
  float dz = zi - v.z;
  float d2 = fmaf(dx, dx, fmaf(dy, dy, dz * dz));
  float qk = v.w;
  if (CHECK) {
    bool take = (jj > i);    // triangle + diagonal guard
    d2 = take ? d2 : 1.0f;   // keep rsq well-defined
    qk = take ? qk : 0.0f;
  }
  float rinv = FRSQ(d2);
  float d = d2 * rinv;
  // erf(d/sqrt2) = 1 - 1/(1 + b1 d + b2 d^2 + b3 d^3 + b4 d^4)^4
  float poly = fmaf(fmaf(fmaf(B4, d, B3), d, B2), d, B1);
  poly = fmaf(poly, d, 1.0f);
  float y = FRCP(poly);
  float y2 = y * y;
  float y4 = y2 * y2;
  float w = fmaf(-y4, rinv, rinv);  // erf(d/sqrt2)/d
  acc = fmaf(qk, w, acc);
}

template <bool CHECK>
__device__ __forceinline__ float tile_sum(const float4* __restrict__ tile,
                                          int jbeg, int i, float xi, float yi,
                                          float zi) {
  // 4 independent accumulator chains, stride-4 interleave
  float acc0 = 0.f, acc1 = 0.f, acc2 = 0.f, acc3 = 0.f;
#pragma unroll 8
  for (int k = 0; k < 32; k += 4) {
    pair_body<CHECK>(tile[k + 0], jbeg + k + 0, i, xi, yi, zi, acc0);
    pair_body<CHECK>(tile[k + 1], jbeg + k + 1, i, xi, yi, zi, acc1);
    pair_body<CHECK>(tile[k + 2], jbeg + k + 2, i, xi, yi, zi, acc2);
    pair_body<CHECK>(tile[k + 3], jbeg + k + 3, i, xi, yi, zi, acc3);
  }
  return (acc0 + acc1) + (acc2 + acc3);
}

__global__ __launch_bounds__(256) void ewald_tri(
    const float* __restrict__ q, const float* __restrict__ r,
    float* __restrict__ partial, int n) {
  const int tid = threadIdx.x;
  const int bid = blockIdx.x;
  const int jslices = (n + 31) >> 5;  // 32-wide j-slices

  // invert bid -> (ib, js): active js for i-block ib are [8*ib, jslices)
  int ib = 0, cum = 0;
  while (true) {
    int c = jslices - 8 * ib;
    if (c <= 0 || cum + c > bid) break;
    cum += c;
    ++ib;
  }
  const int js = 8 * ib + (bid - cum);

  const int ibeg = ib << 8;
  const int jbeg = js << 5;
  const bool pure_above = (jbeg >= ibeg + 256);

  // stage the 32-particle j-tile once (512B)
  __shared__ float4 tile[32];
  if (tid < 32) {
    int j = jbeg + tid;
    float4 v = make_float4(1e10f, 1e10f, 1e10f, 0.f);
    if (j < n) v = make_float4(r[3 * j], r[3 * j + 1], r[3 * j + 2], q[j]);
    tile[tid] = v;
  }

  const int i = ibeg + tid;
  float qi = 0.f, xi = 1e10f, yi = 1e10f, zi = 1e10f;
  if (i < n) {
    qi = q[i];
    xi = r[3 * i];
    yi = r[3 * i + 1];
    zi = r[3 * i + 2];
  }
  __syncthreads();

  float acc;
  if (pure_above)
    acc = tile_sum<false>(tile, jbeg, i, xi, yi, zi);
  else
    acc = tile_sum<true>(tile, jbeg, i, xi, yi, zi);
  acc *= qi;

  // deterministic block reduce: wave shfl, then cross-wave via LDS
  for (int m = 32; m > 0; m >>= 1) acc += __shfl_xor(acc, m, 64);
  __shared__ float wsum[4];
  const int lane = tid & 63;
  const int wid = tid >> 6;
  if (lane == 0) wsum[wid] = acc;
  __syncthreads();
  if (tid == 0)
    partial[bid] = (wsum[0] + wsum[1]) + (wsum[2] + wsum[3]);
}

__global__ __launch_bounds__(1024) void reduce_partials(
    const float* __restrict__ partial, float* __restrict__ out, int np,
    float scale) {
  const int tid = threadIdx.x;
  float acc = 0.f;
  for (int idx = tid; idx < np; idx += 1024) acc += partial[idx];
  for (int m = 32; m > 0; m >>= 1) acc += __shfl_xor(acc, m, 64);
  __shared__ float wsum[16];
  const int lane = tid & 63;
  const int wid = tid >> 6;
  if (lane == 0) wsum[wid] = acc;
  __syncthreads();
  if (tid == 0) {
    float s = 0.f;
    for (int w = 0; w < 16; ++w) s += wsum[w];
    out[0] = s * scale;
  }
}

extern "C" void kernel_launch(void* const* d_in, const int* in_sizes, int n_in,
                              void* d_out, int out_size, void* d_ws,
                              size_t ws_size, hipStream_t stream) {
  const float* q = (const float*)d_in[0];  // [N,1] fp32
  const float* r = (const float*)d_in[1];  // [N,3] fp32
  const int n = in_sizes[0];
  float* out = (float*)d_out;
  float* partial = (float*)d_ws;

  const int iblocks = (n + 255) / 256;
  const int jslices = (n + 31) / 32;
  int nblocks = 0;
  for (int ib = 0; ib < iblocks; ++ib) {
    int c = jslices - 8 * ib;
    if (c > 0) nblocks += c;
  }

  ewald_tri<<<nblocks, 256, 0, stream>>>(q, r, partial, n);

  // 2 (triangle symmetry) * NORM/(2pi)/2 = NORM/(2pi)
  const float scale = (float)(90.0474 / (2.0 * M_PI));
  reduce_partials<<<1, 1024, 0, stream>>>(partial, out, nblocks, scale);
}